// Round 5
// baseline (252.448 us; speedup 1.0000x reference)
//
#include <hip/hip_runtime.h>
#include <hip/hip_bf16.h>
#include <cstdint>

#define N_IMG 4
#define C_CH 32
#define R_RAYS 4096
#define S_SAMP 48
#define M_PTS (R_RAYS * S_SAMP)   // 196608 points per image
#define TOTAL_PTS (N_IMG * M_PTS) // 786432 = 3072*256
#define CELLS_PER_IMG 4096        // 16^3 Morton cells
#define N_CELLS (N_IMG * CELLS_PER_IMG)

typedef float f32x4 __attribute__((ext_vector_type(4)));
typedef unsigned int u32x4 __attribute__((ext_vector_type(4)));

__device__ __forceinline__ unsigned f2bf(float f) {
  __hip_bfloat16 h = __float2bfloat16(f);
  return (unsigned)*reinterpret_cast<unsigned short*>(&h);
}
__device__ __forceinline__ float bflo(unsigned u) { return __uint_as_float(u << 16); }
__device__ __forceinline__ float bfhi(unsigned u) { return __uint_as_float(u & 0xffff0000u); }

// 3D Morton, 4 bits/axis -> 12-bit code
__device__ __forceinline__ unsigned mort4(unsigned x, unsigned y, unsigned z) {
  unsigned r = 0;
#pragma unroll
  for (int b = 0; b < 4; ++b)
    r |= (((x >> b) & 1u) << (3 * b)) | (((y >> b) & 1u) << (3 * b + 1)) |
         (((z >> b) & 1u) << (3 * b + 2));
  return r;
}

__device__ __forceinline__ unsigned cell_key(int idx, const float* __restrict__ coords,
                                             float* X, float* Y, float* Z) {
  *X = coords[idx * 3 + 0] * 2.f;   // grid units in (-0.9, 0.9)
  *Y = coords[idx * 3 + 1] * 2.f;
  *Z = coords[idx * 3 + 2] * 2.f;
  int n = idx / M_PTS;
  unsigned cx = (unsigned)min(max((int)((*X + 0.9f) * (16.f / 1.8f)), 0), 15);
  unsigned cy = (unsigned)min(max((int)((*Y + 0.9f) * (16.f / 1.8f)), 0), 15);
  unsigned cz = (unsigned)min(max((int)((*Z + 0.9f) * (16.f / 1.8f)), 0), 15);
  return (unsigned)n * CELLS_PER_IMG + mort4(cx, cy, cz);
}

// ---------------------------------------------------------------------------
// Sort pass 1: histogram of points per (image, Morton cell)
// ---------------------------------------------------------------------------
__global__ __launch_bounds__(256) void count_cells(
    const float* __restrict__ coords, unsigned* __restrict__ hist) {
  int idx = blockIdx.x * 256 + threadIdx.x;
  float X, Y, Z;
  unsigned key = cell_key(idx, coords, &X, &Y, &Z);
  atomicAdd(&hist[key], 1u);
}

// ---------------------------------------------------------------------------
// Sort pass 2: exclusive scan of 16384 counts (one 1024-thread block)
// ---------------------------------------------------------------------------
__global__ __launch_bounds__(1024) void scan_hist(
    const unsigned* __restrict__ hist, unsigned* __restrict__ cursor) {
  __shared__ unsigned part[1024];
  int t = threadIdx.x;
  unsigned local[16], s = 0;
#pragma unroll
  for (int i = 0; i < 16; ++i) { local[i] = hist[t * 16 + i]; s += local[i]; }
  part[t] = s;
  __syncthreads();
  for (int off = 1; off < 1024; off <<= 1) {
    unsigned v = (t >= off) ? part[t - off] : 0u;
    __syncthreads();
    part[t] += v;
    __syncthreads();
  }
  unsigned ex = (t == 0) ? 0u : part[t - 1];
#pragma unroll
  for (int i = 0; i < 16; ++i) { cursor[t * 16 + i] = ex; ex += local[i]; }
}

// ---------------------------------------------------------------------------
// Sort pass 3: scatter packed {X,Y,Z, orig_idx} records into cell order
// ---------------------------------------------------------------------------
__global__ __launch_bounds__(256) void scatter_sorted(
    const float* __restrict__ coords, unsigned* __restrict__ cursor,
    float4* __restrict__ sorted) {
  int idx = blockIdx.x * 256 + threadIdx.x;
  float X, Y, Z;
  unsigned key = cell_key(idx, coords, &X, &Y, &Z);
  unsigned pos = atomicAdd(&cursor[key], 1u);
  float4 rec;
  rec.x = X; rec.y = Y; rec.z = Z; rec.w = __uint_as_float((unsigned)idx);
  sorted[pos] = rec;
}

// ---------------------------------------------------------------------------
// K0: per-texel head projection, 4 texels/thread, lo+hi in one launch.
// out texel = bf16x4 {sig | r<<16, g | b<<16}. Linear heads commute with
// bilinear sampling and plane/level averaging (exact up to one bf16 round).
// Live-box clip: grid in (-0.9,0.9) -> rows/cols [12,243] (256) / [25,486]
// (512); +-1 margin kept.
// ---------------------------------------------------------------------------
#define LO_BLOCKS 768    // 12*256*256/4/256
#define HI_BLOCKS 3072   // 12*512*512/4/256

__global__ __launch_bounds__(256) void project_planes(
    const float* __restrict__ lo, const float* __restrict__ hi,
    const float* __restrict__ w_sigma, const float* __restrict__ w_rgb,
    uint4* __restrict__ lo_out, uint4* __restrict__ hi_out) {
  __shared__ float sw[4 * C_CH];  // [c*4 + k], k=0 sigma, 1..3 rgb
  int t = threadIdx.x;
  if (t < C_CH) sw[t * 4] = w_sigma[t];
  if (t < 3 * C_CH) sw[(t / 3) * 4 + 1 + (t % 3)] = w_rgb[t];
  __syncthreads();

  int bid = blockIdx.x;
  const float* in;
  uint4* out;
  int logW, g, c0, c1;
  if (bid < LO_BLOCKS) {
    in = lo; out = lo_out; logW = 8; g = bid * 256 + t; c0 = 11; c1 = 244;
  } else {
    in = hi; out = hi_out; logW = 9; g = (bid - LO_BLOCKS) * 256 + t; c0 = 24; c1 = 488;
  }
  int W = 1 << logW;
  int hw = (g * 4) & ((W * W) - 1);
  int np = (g * 4) >> (2 * logW);
  int h = hw >> logW, w = hw & (W - 1);
  if (h < c0 || h > c1 || (w + 3) < c0 || w > c1) return;  // dead margin

  const float* base = in + ((size_t)np << (5 + 2 * logW)) + hw;
  f32x4 as = 0.f, ar = 0.f, ag = 0.f, ab = 0.f;
#pragma unroll
  for (int c = 0; c < C_CH; ++c) {
    f32x4 f;
    __builtin_memcpy(&f, base + ((size_t)c << (2 * logW)), 16);
    as += f * sw[c * 4 + 0];
    ar += f * sw[c * 4 + 1];
    ag += f * sw[c * 4 + 2];
    ab += f * sw[c * 4 + 3];
  }
  uint4 o0, o1;
  o0.x = f2bf(as.x) | (f2bf(ar.x) << 16);
  o0.y = f2bf(ag.x) | (f2bf(ab.x) << 16);
  o0.z = f2bf(as.y) | (f2bf(ar.y) << 16);
  o0.w = f2bf(ag.y) | (f2bf(ab.y) << 16);
  o1.x = f2bf(as.z) | (f2bf(ar.z) << 16);
  o1.y = f2bf(ag.z) | (f2bf(ab.z) << 16);
  o1.z = f2bf(as.w) | (f2bf(ar.w) << 16);
  o1.w = f2bf(ag.w) | (f2bf(ab.w) << 16);
  out[g * 2 + 0] = o0;
  out[g * 2 + 1] = o1;
}

// ---------------------------------------------------------------------------
// K1: gather in Morton-sorted order. XCD-aware block swizzle gives each XCD
// a contiguous sorted range -> its texel working set (~3.2MB) fits its 4MB
// private L2 -> L3 line traffic drops to the compulsory ~26MB.
// Per surface: one 16B load covers both x-corners of a row (12 loads/pt).
// ---------------------------------------------------------------------------
__global__ __launch_bounds__(256) void gather_pts(
    const float4* __restrict__ sorted,
    const uint2* __restrict__ lo_p,   // [12][256][256] texel = 4 bf16
    const uint2* __restrict__ hi_p,   // [12][512][512]
    float4* __restrict__ pts)         // [N*M] {r,g,b,sigma_raw}
{
  int bid = blockIdx.x;                       // 3072 blocks
  int swz = (bid & 7) * (TOTAL_PTS / 256 / 8) + (bid >> 3);  // XCD-contig
  int spos = swz * 256 + threadIdx.x;

  float4 rec = sorted[spos];
  float X = rec.x, Y = rec.y, Z = rec.z;
  unsigned oidx = __float_as_uint(rec.w);
  int n = (int)(oidx / (unsigned)M_PTS);

  float acc0 = 0.f, acc1 = 0.f, acc2 = 0.f, acc3 = 0.f;
  const float gxs[3] = {X, X, Y};
  const float gys[3] = {Y, Z, Z};
  const float gzs[3] = {Z, Y, X};

#pragma unroll
  for (int p = 0; p < 3; ++p) {
    float wz = (1.f - 0.5f * fabsf(gzs[p])) * (1.f / 6.f);
#pragma unroll
    for (int lev = 0; lev < 2; ++lev) {
      const int logW = lev ? 9 : 8;
      const int W = 1 << logW;
      const uint2* pl = lev ? hi_p : lo_p;
      float xf = ((gxs[p] + 1.f) * (float)W - 1.f) * 0.5f;
      float yf = ((gys[p] + 1.f) * (float)W - 1.f) * 0.5f;
      float x0f = floorf(xf), y0f = floorf(yf);
      float fx = xf - x0f, fy = yf - y0f;
      int x0 = (int)x0f, y0 = (int)y0f;
      x0 = min(max(x0, 0), W - 2);           // inputs interior; OOB safety
      y0 = min(max(y0, 0), W - 2);
      int base = ((((n * 3 + p) << logW) + y0) << logW) + x0;
      u32x4 r0, r1;
      __builtin_memcpy(&r0, pl + base, 16);       // texels (y0,   x0..x0+1)
      __builtin_memcpy(&r1, pl + base + W, 16);   // texels (y0+1, x0..x0+1)
      float w00 = wz * (1.f - fy) * (1.f - fx);
      float w01 = wz * (1.f - fy) * fx;
      float w10 = wz * fy * (1.f - fx);
      float w11 = wz * fy * fx;
      acc0 += w00 * bflo(r0.x) + w01 * bflo(r0.z) + w10 * bflo(r1.x) + w11 * bflo(r1.z);
      acc1 += w00 * bfhi(r0.x) + w01 * bfhi(r0.z) + w10 * bfhi(r1.x) + w11 * bfhi(r1.z);
      acc2 += w00 * bflo(r0.y) + w01 * bflo(r0.w) + w10 * bflo(r1.y) + w11 * bflo(r1.w);
      acc3 += w00 * bfhi(r0.y) + w01 * bfhi(r0.w) + w10 * bfhi(r1.y) + w11 * bfhi(r1.w);
    }
  }

  float4 o;
  o.x = 1.f / (1.f + __expf(-acc1));
  o.y = 1.f / (1.f + __expf(-acc2));
  o.z = 1.f / (1.f + __expf(-acc3));
  o.w = acc0;                                 // raw density (pre-softplus)
  pts[oidx] = o;
}

// ---------------------------------------------------------------------------
// K2: alpha compositing, one thread per ray (768B contiguous per thread).
// ---------------------------------------------------------------------------
__global__ __launch_bounds__(256) void ray_march_k(
    const float4* __restrict__ pts, const float* __restrict__ depths,
    float* __restrict__ out) {
  int t = blockIdx.x * 256 + threadIdx.x;    // < N*R
  const float4* p = pts + (size_t)t * S_SAMP;
  const float* d = depths + (size_t)t * S_SAMP;

  float4 prev = p[0];
  float dprev = d[0];
  float T = 1.f, accR = 0.f, accG = 0.f, accB = 0.f;
#pragma unroll 4
  for (int i = 1; i < S_SAMP; ++i) {
    float4 cur = p[i];
    float dcur = d[i];
    float delta = dcur - dprev;
    float cr = 0.5f * (prev.x + cur.x);
    float cg = 0.5f * (prev.y + cur.y);
    float cb = 0.5f * (prev.z + cur.z);
    float dm = 0.5f * (prev.w + cur.w) - 1.f;
    float sp = fmaxf(dm, 0.f) + log1pf(__expf(-fabsf(dm)));  // softplus
    float a = 1.f - __expf(-sp * delta);
    float w = a * T;
    accR += w * cr; accG += w * cg; accB += w * cb;
    T *= (1.f - a + 1e-10f);
    prev = cur; dprev = dcur;
  }
  out[t * 3 + 0] = accR;
  out[t * 3 + 1] = accG;
  out[t * 3 + 2] = accB;
}

// ---------------------------------------------------------------------------
extern "C" void kernel_launch(void* const* d_in, const int* in_sizes, int n_in,
                              void* d_out, int out_size, void* d_ws, size_t ws_size,
                              hipStream_t stream) {
  const float* plane_lo = (const float*)d_in[0];  // [4,3,32,256,256]
  const float* plane_hi = (const float*)d_in[1];  // [4,3,32,512,512]
  const float* coords   = (const float*)d_in[2];  // [4,196608,3]
  const float* depths   = (const float*)d_in[3];  // [4,4096,48,1]
  const float* w_sigma  = (const float*)d_in[4];  // [32,1]
  const float* w_rgb    = (const float*)d_in[5];  // [32,3]

  const size_t LO_TEX = (size_t)12 * 256 * 256;   //   786,432 texels
  const size_t HI_TEX = (size_t)12 * 512 * 512;   // 3,145,728 texels
  char* ws = (char*)d_ws;
  uint2* lo_p   = (uint2*)ws;                                    //  6.3 MB
  uint2* hi_p   = (uint2*)(ws + LO_TEX * 8);                     // 25.2 MB
  float4* pts   = (float4*)(ws + (LO_TEX + HI_TEX) * 8);         // 12.6 MB
  float4* sorted= (float4*)(ws + (LO_TEX + HI_TEX) * 8 + (size_t)TOTAL_PTS * 16);
  unsigned* hist   = (unsigned*)((char*)sorted + (size_t)TOTAL_PTS * 16);
  unsigned* cursor = hist + N_CELLS;
  // total ws use: 6.3 + 25.2 + 12.6 + 12.6 MB + 128KB

  hipMemsetAsync(hist, 0, N_CELLS * sizeof(unsigned), stream);

  count_cells<<<TOTAL_PTS / 256, 256, 0, stream>>>(coords, hist);
  scan_hist<<<1, 1024, 0, stream>>>(hist, cursor);
  scatter_sorted<<<TOTAL_PTS / 256, 256, 0, stream>>>(coords, cursor, sorted);

  project_planes<<<LO_BLOCKS + HI_BLOCKS, 256, 0, stream>>>(
      plane_lo, plane_hi, w_sigma, w_rgb, (uint4*)lo_p, (uint4*)hi_p);

  gather_pts<<<TOTAL_PTS / 256, 256, 0, stream>>>(sorted, lo_p, hi_p, pts);

  ray_march_k<<<(N_IMG * R_RAYS) / 256, 256, 0, stream>>>(
      pts, depths, (float*)d_out);
}

// Round 6
// 192.016 us; speedup vs baseline: 1.3147x; 1.3147x over previous
//
#include <hip/hip_runtime.h>
#include <hip/hip_bf16.h>
#include <cstdint>

#define N_IMG 4
#define C_CH 32
#define R_RAYS 4096
#define S_SAMP 48
#define M_PTS (R_RAYS * S_SAMP)   // 196608 points per image

typedef float f32x4 __attribute__((ext_vector_type(4)));

__device__ __forceinline__ unsigned f2bf(float f) {
  __hip_bfloat16 h = __float2bfloat16(f);
  return (unsigned)*reinterpret_cast<unsigned short*>(&h);
}
__device__ __forceinline__ float bflo(unsigned u) { return __uint_as_float(u << 16); }
__device__ __forceinline__ float bfhi(unsigned u) { return __uint_as_float(u & 0xffff0000u); }

// ---------------------------------------------------------------------------
// Texel layout: 4x4-texel tiles, one tile = 16 texels x 8B = one 128B line.
// texel(x,y) lives at plane_base + (((y>>2)<<logT)+(x>>2))*16 + ((y&3)<<2)+(x&3)
// where logT = logW-2. A 2x2 bilinear footprint touches E=1.56 lines vs 2.125
// for row-major -> 26% less L3->L2 line traffic (the gather's bound resource).
// ---------------------------------------------------------------------------

// ---------------------------------------------------------------------------
// K0: per-texel head projection, 4 texels/thread (one tile row = 32B out),
// lo+hi in one launch. out texel = bf16x4 {sig | r<<16, g | b<<16}.
// Linear heads commute with bilinear sampling and plane/level averaging
// (exact up to one bf16 round). Live-box clip: grid in (-0.9,0.9) ->
// rows/cols [12,243] (256) / [25,486] (512); +-1 margin kept.
// Non-temporal plane reads: pure streaming, keep L3 for the texel set.
// ---------------------------------------------------------------------------
#define LO_BLOCKS 768    // 12*256*256/4/256
#define HI_BLOCKS 3072   // 12*512*512/4/256

__global__ __launch_bounds__(256) void project_planes(
    const float* __restrict__ lo, const float* __restrict__ hi,
    const float* __restrict__ w_sigma, const float* __restrict__ w_rgb,
    uint4* __restrict__ lo_out, uint4* __restrict__ hi_out) {
  __shared__ float sw[4 * C_CH];  // [c*4 + k], k=0 sigma, 1..3 rgb
  int t = threadIdx.x;
  if (t < C_CH) sw[t * 4] = w_sigma[t];
  if (t < 3 * C_CH) sw[(t / 3) * 4 + 1 + (t % 3)] = w_rgb[t];
  __syncthreads();

  int bid = blockIdx.x;
  const float* in;
  uint4* out;
  int logW, g, c0, c1;
  if (bid < LO_BLOCKS) {
    in = lo; out = lo_out; logW = 8; g = bid * 256 + t; c0 = 11; c1 = 244;
  } else {
    in = hi; out = hi_out; logW = 9; g = (bid - LO_BLOCKS) * 256 + t; c0 = 24; c1 = 488;
  }
  int W = 1 << logW;
  int hw = (g * 4) & ((W * W) - 1);
  int np = (g * 4) >> (2 * logW);
  int h = hw >> logW, w = hw & (W - 1);      // w is a multiple of 4
  if (h < c0 || h > c1 || (w + 3) < c0 || w > c1) return;  // dead margin

  const float* base = in + ((size_t)np << (5 + 2 * logW)) + hw;
  f32x4 as = 0.f, ar = 0.f, ag = 0.f, ab = 0.f;
#pragma unroll
  for (int c = 0; c < C_CH; ++c) {
    f32x4 f = __builtin_nontemporal_load(
        reinterpret_cast<const f32x4*>(base + ((size_t)c << (2 * logW))));
    as += f * sw[c * 4 + 0];
    ar += f * sw[c * 4 + 1];
    ag += f * sw[c * 4 + 2];
    ab += f * sw[c * 4 + 3];
  }
  uint4 o0, o1;
  o0.x = f2bf(as.x) | (f2bf(ar.x) << 16);
  o0.y = f2bf(ag.x) | (f2bf(ab.x) << 16);
  o0.z = f2bf(as.y) | (f2bf(ar.y) << 16);
  o0.w = f2bf(ag.y) | (f2bf(ab.y) << 16);
  o1.x = f2bf(as.z) | (f2bf(ar.z) << 16);
  o1.y = f2bf(ag.z) | (f2bf(ab.z) << 16);
  o1.z = f2bf(as.w) | (f2bf(ar.w) << 16);
  o1.w = f2bf(ag.w) | (f2bf(ab.w) << 16);
  // tiled output: tile row (h&3) of tile (h>>2, w>>2) = 32B contiguous
  int logT = logW - 2;
  int tex = np * (W * W) + ((((h >> 2) << logT) + (w >> 2)) << 4) + ((h & 3) << 2);
  int uidx = tex >> 1;                        // uint4 = 2 texels
  out[uidx] = o0;
  out[uidx + 1] = o1;
}

// ---------------------------------------------------------------------------
// K1: per-point triplane gather (1 pt/thread), tiled-layout texel fetch:
// 4 x 8B loads per surface, E[128B lines] = 1.56 per bilinear footprint.
// ---------------------------------------------------------------------------
__global__ __launch_bounds__(256) void gather_pts(
    const float* __restrict__ coords,
    const uint2* __restrict__ lo_p,   // [12] tiled 256x256, texel = 4 bf16
    const uint2* __restrict__ hi_p,   // [12] tiled 512x512
    float4* __restrict__ pts)         // [N*M] {r,g,b,sigma_raw}
{
  int idx = blockIdx.x * 256 + threadIdx.x;   // < N*M exactly
  int n = idx / M_PTS;

  float X = coords[idx * 3 + 0] * 2.f;
  float Y = coords[idx * 3 + 1] * 2.f;
  float Z = coords[idx * 3 + 2] * 2.f;

  float acc0 = 0.f, acc1 = 0.f, acc2 = 0.f, acc3 = 0.f;
  const float gxs[3] = {X, X, Y};
  const float gys[3] = {Y, Z, Z};
  const float gzs[3] = {Z, Y, X};

#pragma unroll
  for (int p = 0; p < 3; ++p) {
    float wz = (1.f - 0.5f * fabsf(gzs[p])) * (1.f / 6.f);  // depth wt, /2 maps /3 planes
#pragma unroll
    for (int lev = 0; lev < 2; ++lev) {
      const int logW = lev ? 9 : 8;
      const int logT = logW - 2;
      const int W = 1 << logW;
      const uint2* pl = lev ? hi_p : lo_p;
      float xf = ((gxs[p] + 1.f) * (float)W - 1.f) * 0.5f;
      float yf = ((gys[p] + 1.f) * (float)W - 1.f) * 0.5f;
      float x0f = floorf(xf), y0f = floorf(yf);
      float fx = xf - x0f, fy = yf - y0f;
      int x0 = (int)x0f, y0 = (int)y0f;
      x0 = min(max(x0, 0), W - 2);           // inputs interior; OOB safety only
      y0 = min(max(y0, 0), W - 2);
      int x1 = x0 + 1, y1 = y0 + 1;
      int pb = (n * 3 + p) << (2 * logW);    // plane base (texels)
      int a00 = pb + ((((y0 >> 2) << logT) + (x0 >> 2)) << 4) + ((y0 & 3) << 2) + (x0 & 3);
      int a01 = pb + ((((y0 >> 2) << logT) + (x1 >> 2)) << 4) + ((y0 & 3) << 2) + (x1 & 3);
      int a10 = pb + ((((y1 >> 2) << logT) + (x0 >> 2)) << 4) + ((y1 & 3) << 2) + (x0 & 3);
      int a11 = pb + ((((y1 >> 2) << logT) + (x1 >> 2)) << 4) + ((y1 & 3) << 2) + (x1 & 3);
      uint2 t00 = pl[a00], t01 = pl[a01], t10 = pl[a10], t11 = pl[a11];
      float w00 = wz * (1.f - fy) * (1.f - fx);
      float w01 = wz * (1.f - fy) * fx;
      float w10 = wz * fy * (1.f - fx);
      float w11 = wz * fy * fx;
      acc0 += w00 * bflo(t00.x) + w01 * bflo(t01.x) + w10 * bflo(t10.x) + w11 * bflo(t11.x);
      acc1 += w00 * bfhi(t00.x) + w01 * bfhi(t01.x) + w10 * bfhi(t10.x) + w11 * bfhi(t11.x);
      acc2 += w00 * bflo(t00.y) + w01 * bflo(t01.y) + w10 * bflo(t10.y) + w11 * bflo(t11.y);
      acc3 += w00 * bfhi(t00.y) + w01 * bfhi(t01.y) + w10 * bfhi(t10.y) + w11 * bfhi(t11.y);
    }
  }

  float4 o;
  o.x = 1.f / (1.f + __expf(-acc1));
  o.y = 1.f / (1.f + __expf(-acc2));
  o.z = 1.f / (1.f + __expf(-acc3));
  o.w = acc0;                                 // raw density (pre-softplus)
  pts[idx] = o;
}

// ---------------------------------------------------------------------------
// K2: alpha compositing, one thread per ray (768B contiguous per thread).
// ---------------------------------------------------------------------------
__global__ __launch_bounds__(256) void ray_march_k(
    const float4* __restrict__ pts, const float* __restrict__ depths,
    float* __restrict__ out) {
  int t = blockIdx.x * 256 + threadIdx.x;    // < N*R
  const float4* p = pts + (size_t)t * S_SAMP;
  const float* d = depths + (size_t)t * S_SAMP;

  float4 prev = p[0];
  float dprev = d[0];
  float T = 1.f, accR = 0.f, accG = 0.f, accB = 0.f;
#pragma unroll 4
  for (int i = 1; i < S_SAMP; ++i) {
    float4 cur = p[i];
    float dcur = d[i];
    float delta = dcur - dprev;
    float cr = 0.5f * (prev.x + cur.x);
    float cg = 0.5f * (prev.y + cur.y);
    float cb = 0.5f * (prev.z + cur.z);
    float dm = 0.5f * (prev.w + cur.w) - 1.f;
    float sp = fmaxf(dm, 0.f) + log1pf(__expf(-fabsf(dm)));  // softplus
    float a = 1.f - __expf(-sp * delta);
    float w = a * T;
    accR += w * cr; accG += w * cg; accB += w * cb;
    T *= (1.f - a + 1e-10f);
    prev = cur; dprev = dcur;
  }
  out[t * 3 + 0] = accR;
  out[t * 3 + 1] = accG;
  out[t * 3 + 2] = accB;
}

// ---------------------------------------------------------------------------
extern "C" void kernel_launch(void* const* d_in, const int* in_sizes, int n_in,
                              void* d_out, int out_size, void* d_ws, size_t ws_size,
                              hipStream_t stream) {
  const float* plane_lo = (const float*)d_in[0];  // [4,3,32,256,256]
  const float* plane_hi = (const float*)d_in[1];  // [4,3,32,512,512]
  const float* coords   = (const float*)d_in[2];  // [4,196608,3]
  const float* depths   = (const float*)d_in[3];  // [4,4096,48,1]
  const float* w_sigma  = (const float*)d_in[4];  // [32,1]
  const float* w_rgb    = (const float*)d_in[5];  // [32,3]

  const size_t LO_TEX = (size_t)12 * 256 * 256;   //   786,432 texels
  const size_t HI_TEX = (size_t)12 * 512 * 512;   // 3,145,728 texels
  char* ws = (char*)d_ws;
  uint2* lo_p = (uint2*)ws;                               //  6.3 MB
  uint2* hi_p = (uint2*)(ws + LO_TEX * 8);                // 25.2 MB
  float4* pts = (float4*)(ws + (LO_TEX + HI_TEX) * 8);    // 12.6 MB

  project_planes<<<LO_BLOCKS + HI_BLOCKS, 256, 0, stream>>>(
      plane_lo, plane_hi, w_sigma, w_rgb, (uint4*)lo_p, (uint4*)hi_p);

  gather_pts<<<(N_IMG * M_PTS) / 256, 256, 0, stream>>>(
      coords, lo_p, hi_p, pts);

  ray_march_k<<<(N_IMG * R_RAYS) / 256, 256, 0, stream>>>(
      pts, depths, (float*)d_out);
}

// Round 7
// 178.207 us; speedup vs baseline: 1.4166x; 1.0775x over previous
//
#include <hip/hip_runtime.h>
#include <hip/hip_bf16.h>
#include <cstdint>

#define N_IMG 4
#define C_CH 32
#define R_RAYS 4096
#define S_SAMP 48
#define M_PTS (R_RAYS * S_SAMP)   // 196608 points per image
#define BLKS_PER_IMG 768          // 196608 / 256

typedef float f32x4 __attribute__((ext_vector_type(4)));
typedef unsigned int u32x4 __attribute__((ext_vector_type(4)));

__device__ __forceinline__ unsigned f2bf(float f) {
  __hip_bfloat16 h = __float2bfloat16(f);
  return (unsigned)*reinterpret_cast<unsigned short*>(&h);
}
__device__ __forceinline__ float bflo(unsigned u) { return __uint_as_float(u << 16); }
__device__ __forceinline__ float bfhi(unsigned u) { return __uint_as_float(u & 0xffff0000u); }

// ---------------------------------------------------------------------------
// K0: per-texel head projection, 4 texels/thread, lo+hi in one launch.
// in:  f32 [NP=12, C=32, H, W];  out row-major bf16x4 [NP, H, W] packed texel
// {sig | r<<16, g | b<<16}. Linear heads commute with bilinear sampling and
// plane/level averaging -> gathering the 4 projections is exact up to one
// bf16 rounding. Live-box clip: grid in (-0.9,0.9) -> rows/cols [12,243]
// (W=256) / [25,486] (W=512); +-1 margin kept.
// ---------------------------------------------------------------------------
#define LO_BLOCKS 768    // 12*256*256/4/256
#define HI_BLOCKS 3072   // 12*512*512/4/256

__global__ __launch_bounds__(256) void project_planes(
    const float* __restrict__ lo, const float* __restrict__ hi,
    const float* __restrict__ w_sigma, const float* __restrict__ w_rgb,
    uint4* __restrict__ lo_out, uint4* __restrict__ hi_out) {
  __shared__ float sw[4 * C_CH];  // [c*4 + k], k=0 sigma, 1..3 rgb
  int t = threadIdx.x;
  if (t < C_CH) sw[t * 4] = w_sigma[t];
  if (t < 3 * C_CH) sw[(t / 3) * 4 + 1 + (t % 3)] = w_rgb[t];
  __syncthreads();

  int bid = blockIdx.x;
  const float* in;
  uint4* out;
  int logW, g, c0, c1;
  if (bid < LO_BLOCKS) {
    in = lo; out = lo_out; logW = 8; g = bid * 256 + t; c0 = 11; c1 = 244;
  } else {
    in = hi; out = hi_out; logW = 9; g = (bid - LO_BLOCKS) * 256 + t; c0 = 24; c1 = 488;
  }
  int W = 1 << logW;
  int hw = (g * 4) & ((W * W) - 1);
  int np = (g * 4) >> (2 * logW);
  int h = hw >> logW, w = hw & (W - 1);
  if (h < c0 || h > c1 || (w + 3) < c0 || w > c1) return;  // dead margin

  const float* base = in + ((size_t)np << (5 + 2 * logW)) + hw;
  f32x4 as = 0.f, ar = 0.f, ag = 0.f, ab = 0.f;
#pragma unroll
  for (int c = 0; c < C_CH; ++c) {
    f32x4 f;
    __builtin_memcpy(&f, base + ((size_t)c << (2 * logW)), 16);
    as += f * sw[c * 4 + 0];
    ar += f * sw[c * 4 + 1];
    ag += f * sw[c * 4 + 2];
    ab += f * sw[c * 4 + 3];
  }
  uint4 o0, o1;
  o0.x = f2bf(as.x) | (f2bf(ar.x) << 16);
  o0.y = f2bf(ag.x) | (f2bf(ab.x) << 16);
  o0.z = f2bf(as.y) | (f2bf(ar.y) << 16);
  o0.w = f2bf(ag.y) | (f2bf(ab.y) << 16);
  o1.x = f2bf(as.z) | (f2bf(ar.z) << 16);
  o1.y = f2bf(ag.z) | (f2bf(ab.z) << 16);
  o1.z = f2bf(as.w) | (f2bf(ar.w) << 16);
  o1.w = f2bf(ag.w) | (f2bf(ab.w) << 16);
  out[g * 2 + 0] = o0;
  out[g * 2 + 1] = o1;
}

// ---------------------------------------------------------------------------
// K1: gather, split into surface passes so each XCD's random working set
// fits its private 4MB L2.
//  - LEV=0, PLANE=-1: all 3 lo planes (first pass, initializes acc)
//  - LEV=1, PLANE=p : one hi plane   (accumulates; LAST applies sigmoid)
// XCD-image affinity: blockIdx round-robins across the 8 XCDs, so
// img=(bid&7)>>1 pins each XCD to one image -> working set/XCD = 2MB (hi)
// or 1.5MB (lo), L2-resident. Mapping is bijective on [0,3072) blocks.
// acc layout in pts during passes: {sigma, r_logit, g_logit, b_logit};
// LAST pass rewrites as {r,g,b,sigma_raw} for the ray-marcher.
// ---------------------------------------------------------------------------
template <int LEV, int PLANE, bool FIRST, bool LAST>
__global__ __launch_bounds__(256) void gather_pass(
    const float* __restrict__ coords,
    const uint2* __restrict__ tex,    // texel array for this level
    float4* __restrict__ pts) {
  int bid = blockIdx.x;                          // 3072
  int n = (bid & 7) >> 1;                        // image per XCD pair
  int blk = ((bid >> 3) << 1) + (bid & 1);       // 0..767 within image
  int idx = (n * BLKS_PER_IMG + blk) * 256 + threadIdx.x;

  float X = coords[idx * 3 + 0] * 2.f;
  float Y = coords[idx * 3 + 1] * 2.f;
  float Z = coords[idx * 3 + 2] * 2.f;

  float4 acc;
  if (FIRST) { acc.x = 0.f; acc.y = 0.f; acc.z = 0.f; acc.w = 0.f; }
  else acc = pts[idx];

  const float gxs[3] = {X, X, Y};
  const float gys[3] = {Y, Z, Z};
  const float gzs[3] = {Z, Y, X};

#pragma unroll
  for (int p = 0; p < 3; ++p) {
    if (PLANE >= 0 && p != PLANE) continue;
    float wz = (1.f - 0.5f * fabsf(gzs[p])) * (1.f / 6.f);  // depth wt, /2 maps /3 planes
    const int logW = LEV ? 9 : 8;
    const int W = 1 << logW;
    float xf = ((gxs[p] + 1.f) * (float)W - 1.f) * 0.5f;
    float yf = ((gys[p] + 1.f) * (float)W - 1.f) * 0.5f;
    float x0f = floorf(xf), y0f = floorf(yf);
    float fx = xf - x0f, fy = yf - y0f;
    int x0 = (int)x0f, y0 = (int)y0f;
    x0 = min(max(x0, 0), W - 2);                 // inputs interior; OOB safety
    y0 = min(max(y0, 0), W - 2);
    int base = ((((n * 3 + p) << logW) + y0) << logW) + x0;
    u32x4 r0, r1;
    __builtin_memcpy(&r0, tex + base, 16);       // texels (y0,   x0..x0+1)
    __builtin_memcpy(&r1, tex + base + W, 16);   // texels (y0+1, x0..x0+1)
    float w00 = wz * (1.f - fy) * (1.f - fx);
    float w01 = wz * (1.f - fy) * fx;
    float w10 = wz * fy * (1.f - fx);
    float w11 = wz * fy * fx;
    acc.x += w00 * bflo(r0.x) + w01 * bflo(r0.z) + w10 * bflo(r1.x) + w11 * bflo(r1.z);
    acc.y += w00 * bfhi(r0.x) + w01 * bfhi(r0.z) + w10 * bfhi(r1.x) + w11 * bfhi(r1.z);
    acc.z += w00 * bflo(r0.y) + w01 * bflo(r0.w) + w10 * bflo(r1.y) + w11 * bflo(r1.w);
    acc.w += w00 * bfhi(r0.y) + w01 * bfhi(r0.w) + w10 * bfhi(r1.y) + w11 * bfhi(r1.w);
  }

  if (LAST) {
    float4 o;
    o.x = 1.f / (1.f + __expf(-acc.y));
    o.y = 1.f / (1.f + __expf(-acc.z));
    o.z = 1.f / (1.f + __expf(-acc.w));
    o.w = acc.x;                                 // raw density (pre-softplus)
    pts[idx] = o;
  } else {
    pts[idx] = acc;
  }
}

// ---------------------------------------------------------------------------
// K2: alpha compositing, one thread per ray (768B contiguous per thread).
// ---------------------------------------------------------------------------
__global__ __launch_bounds__(256) void ray_march_k(
    const float4* __restrict__ pts, const float* __restrict__ depths,
    float* __restrict__ out) {
  int t = blockIdx.x * 256 + threadIdx.x;    // < N*R
  const float4* p = pts + (size_t)t * S_SAMP;
  const float* d = depths + (size_t)t * S_SAMP;

  float4 prev = p[0];
  float dprev = d[0];
  float T = 1.f, accR = 0.f, accG = 0.f, accB = 0.f;
#pragma unroll 4
  for (int i = 1; i < S_SAMP; ++i) {
    float4 cur = p[i];
    float dcur = d[i];
    float delta = dcur - dprev;
    float cr = 0.5f * (prev.x + cur.x);
    float cg = 0.5f * (prev.y + cur.y);
    float cb = 0.5f * (prev.z + cur.z);
    float dm = 0.5f * (prev.w + cur.w) - 1.f;
    float sp = fmaxf(dm, 0.f) + log1pf(__expf(-fabsf(dm)));  // softplus
    float a = 1.f - __expf(-sp * delta);
    float w = a * T;
    accR += w * cr; accG += w * cg; accB += w * cb;
    T *= (1.f - a + 1e-10f);
    prev = cur; dprev = dcur;
  }
  out[t * 3 + 0] = accR;
  out[t * 3 + 1] = accG;
  out[t * 3 + 2] = accB;
}

// ---------------------------------------------------------------------------
extern "C" void kernel_launch(void* const* d_in, const int* in_sizes, int n_in,
                              void* d_out, int out_size, void* d_ws, size_t ws_size,
                              hipStream_t stream) {
  const float* plane_lo = (const float*)d_in[0];  // [4,3,32,256,256]
  const float* plane_hi = (const float*)d_in[1];  // [4,3,32,512,512]
  const float* coords   = (const float*)d_in[2];  // [4,196608,3]
  const float* depths   = (const float*)d_in[3];  // [4,4096,48,1]
  const float* w_sigma  = (const float*)d_in[4];  // [32,1]
  const float* w_rgb    = (const float*)d_in[5];  // [32,3]

  const size_t LO_TEX = (size_t)12 * 256 * 256;   //   786,432 texels
  const size_t HI_TEX = (size_t)12 * 512 * 512;   // 3,145,728 texels
  char* ws = (char*)d_ws;
  uint2* lo_p = (uint2*)ws;                               //  6.3 MB
  uint2* hi_p = (uint2*)(ws + LO_TEX * 8);                // 25.2 MB
  float4* pts = (float4*)(ws + (LO_TEX + HI_TEX) * 8);    // 12.6 MB

  project_planes<<<LO_BLOCKS + HI_BLOCKS, 256, 0, stream>>>(
      plane_lo, plane_hi, w_sigma, w_rgb, (uint4*)lo_p, (uint4*)hi_p);

  const int GB = N_IMG * BLKS_PER_IMG;  // 3072
  gather_pass<0, -1, true,  false><<<GB, 256, 0, stream>>>(coords, lo_p, pts);
  gather_pass<1,  0, false, false><<<GB, 256, 0, stream>>>(coords, hi_p, pts);
  gather_pass<1,  1, false, false><<<GB, 256, 0, stream>>>(coords, hi_p, pts);
  gather_pass<1,  2, false, true ><<<GB, 256, 0, stream>>>(coords, hi_p, pts);

  ray_march_k<<<(N_IMG * R_RAYS) / 256, 256, 0, stream>>>(
      pts, depths, (float*)d_out);
}

// Round 9
// 172.727 us; speedup vs baseline: 1.4615x; 1.0317x over previous
//
#include <hip/hip_runtime.h>
#include <hip/hip_bf16.h>
#include <cstdint>

#define N_IMG 4
#define C_CH 32
#define R_RAYS 4096
#define S_SAMP 48
#define M_PTS (R_RAYS * S_SAMP)   // 196608 points per image
#define TOTAL_PTS (N_IMG * M_PTS) // 786432

typedef float f32x4 __attribute__((ext_vector_type(4)));
typedef unsigned int u32x4 __attribute__((ext_vector_type(4)));
typedef unsigned int u32x2 __attribute__((ext_vector_type(2)));

__device__ __forceinline__ unsigned f2bf(float f) {
  __hip_bfloat16 h = __float2bfloat16(f);
  return (unsigned)*reinterpret_cast<unsigned short*>(&h);
}
__device__ __forceinline__ float bflo(unsigned u) { return __uint_as_float(u << 16); }
__device__ __forceinline__ float bfhi(unsigned u) { return __uint_as_float(u & 0xffff0000u); }

// ---------------------------------------------------------------------------
// K0: per-texel head projection, 4 texels/thread, lo+hi in one launch.
// in:  f32 [NP=12, C=32, H, W];  out row-major bf16x4 [NP, H, W] packed texel
// {sig | r<<16, g | b<<16}. Linear heads commute with bilinear sampling and
// plane/level averaging -> gathering the 4 projections is exact up to one
// bf16 rounding. Live-box clip: grid in (-0.9,0.9) -> rows/cols [12,243]
// (W=256) / [25,486] (W=512); +-1 margin kept.
// ---------------------------------------------------------------------------
#define LO_BLOCKS 768    // 12*256*256/4/256
#define HI_BLOCKS 3072   // 12*512*512/4/256

__global__ __launch_bounds__(256) void project_planes(
    const float* __restrict__ lo, const float* __restrict__ hi,
    const float* __restrict__ w_sigma, const float* __restrict__ w_rgb,
    uint4* __restrict__ lo_out, uint4* __restrict__ hi_out) {
  __shared__ float sw[4 * C_CH];  // [c*4 + k], k=0 sigma, 1..3 rgb
  int t = threadIdx.x;
  if (t < C_CH) sw[t * 4] = w_sigma[t];
  if (t < 3 * C_CH) sw[(t / 3) * 4 + 1 + (t % 3)] = w_rgb[t];
  __syncthreads();

  int bid = blockIdx.x;
  const float* in;
  uint4* out;
  int logW, g, c0, c1;
  if (bid < LO_BLOCKS) {
    in = lo; out = lo_out; logW = 8; g = bid * 256 + t; c0 = 11; c1 = 244;
  } else {
    in = hi; out = hi_out; logW = 9; g = (bid - LO_BLOCKS) * 256 + t; c0 = 24; c1 = 488;
  }
  int W = 1 << logW;
  int hw = (g * 4) & ((W * W) - 1);
  int np = (g * 4) >> (2 * logW);
  int h = hw >> logW, w = hw & (W - 1);
  if (h < c0 || h > c1 || (w + 3) < c0 || w > c1) return;  // dead margin

  const float* base = in + ((size_t)np << (5 + 2 * logW)) + hw;
  f32x4 as = 0.f, ar = 0.f, ag = 0.f, ab = 0.f;
#pragma unroll
  for (int c = 0; c < C_CH; ++c) {
    f32x4 f;
    __builtin_memcpy(&f, base + ((size_t)c << (2 * logW)), 16);
    as += f * sw[c * 4 + 0];
    ar += f * sw[c * 4 + 1];
    ag += f * sw[c * 4 + 2];
    ab += f * sw[c * 4 + 3];
  }
  uint4 o0, o1;
  o0.x = f2bf(as.x) | (f2bf(ar.x) << 16);
  o0.y = f2bf(ag.x) | (f2bf(ab.x) << 16);
  o0.z = f2bf(as.y) | (f2bf(ar.y) << 16);
  o0.w = f2bf(ag.y) | (f2bf(ab.y) << 16);
  o1.x = f2bf(as.z) | (f2bf(ar.z) << 16);
  o1.y = f2bf(ag.z) | (f2bf(ab.z) << 16);
  o1.z = f2bf(as.w) | (f2bf(ar.w) << 16);
  o1.w = f2bf(ag.w) | (f2bf(ab.w) << 16);
  out[g * 2 + 0] = o0;
  out[g * 2 + 1] = o1;
}

// ---------------------------------------------------------------------------
// Gather: 2 passes (lo 3-planes, hi 3-planes), 2 points/thread for doubled
// memory-level parallelism. XCD-image affinity: bid&7 -> XCD (round-robin
// dispatch), so (bid&7)>>1 pins each XCD to one image's texel set.
// Streams (coords, mid, pts) use non-temporal hints so they don't evict
// the texel set from L2. Intermediate logits stored bf16 (u32x2, 6.3MB).
// ---------------------------------------------------------------------------
__device__ __forceinline__ void surf_accum(
    const uint2* __restrict__ tex, int pb, int logW,
    float gx, float gy, float wz, float* acc) {
  const int W = 1 << logW;
  float xf = ((gx + 1.f) * (float)W - 1.f) * 0.5f;
  float yf = ((gy + 1.f) * (float)W - 1.f) * 0.5f;
  float x0f = floorf(xf), y0f = floorf(yf);
  float fx = xf - x0f, fy = yf - y0f;
  int x0 = (int)x0f, y0 = (int)y0f;
  x0 = min(max(x0, 0), W - 2);               // inputs interior; OOB safety
  y0 = min(max(y0, 0), W - 2);
  int base = pb + (y0 << logW) + x0;
  u32x4 r0, r1;
  __builtin_memcpy(&r0, tex + base, 16);     // texels (y0,   x0..x0+1)
  __builtin_memcpy(&r1, tex + base + W, 16); // texels (y0+1, x0..x0+1)
  float w00 = wz * (1.f - fy) * (1.f - fx);
  float w01 = wz * (1.f - fy) * fx;
  float w10 = wz * fy * (1.f - fx);
  float w11 = wz * fy * fx;
  acc[0] += w00 * bflo(r0.x) + w01 * bflo(r0.z) + w10 * bflo(r1.x) + w11 * bflo(r1.z);
  acc[1] += w00 * bfhi(r0.x) + w01 * bfhi(r0.z) + w10 * bfhi(r1.x) + w11 * bfhi(r1.z);
  acc[2] += w00 * bflo(r0.y) + w01 * bflo(r0.w) + w10 * bflo(r1.y) + w11 * bflo(r1.w);
  acc[3] += w00 * bfhi(r0.y) + w01 * bfhi(r0.w) + w10 * bfhi(r1.y) + w11 * bfhi(r1.w);
}

__global__ __launch_bounds__(256) void gather_lo(
    const float* __restrict__ coords,
    const uint2* __restrict__ lo_p,     // [12][256][256] texel = 4 bf16
    unsigned* __restrict__ mid) {       // [N*M] bf16x4 partial logits (2 u32)
  int bid = blockIdx.x;                       // 1536
  int n = (bid & 7) >> 1;                     // image per XCD pair
  int blk = ((bid >> 3) << 1) + (bid & 1);    // 0..383 within image
  int base = n * M_PTS + blk * 512 + threadIdx.x;

  float acc[2][4];
#pragma unroll
  for (int q = 0; q < 2; ++q) {
    int idx = base + q * 256;
    float X = __builtin_nontemporal_load(coords + idx * 3 + 0) * 2.f;
    float Y = __builtin_nontemporal_load(coords + idx * 3 + 1) * 2.f;
    float Z = __builtin_nontemporal_load(coords + idx * 3 + 2) * 2.f;
    acc[q][0] = 0.f; acc[q][1] = 0.f; acc[q][2] = 0.f; acc[q][3] = 0.f;
    const float gxs[3] = {X, X, Y};
    const float gys[3] = {Y, Z, Z};
    const float gzs[3] = {Z, Y, X};
#pragma unroll
    for (int p = 0; p < 3; ++p) {
      float wz = (1.f - 0.5f * fabsf(gzs[p])) * (1.f / 6.f);
      surf_accum(lo_p, (n * 3 + p) << 16, 8, gxs[p], gys[p], wz, acc[q]);
    }
  }
#pragma unroll
  for (int q = 0; q < 2; ++q) {
    u32x2 m;
    m.x = f2bf(acc[q][0]) | (f2bf(acc[q][1]) << 16);
    m.y = f2bf(acc[q][2]) | (f2bf(acc[q][3]) << 16);
    __builtin_nontemporal_store(
        m, reinterpret_cast<u32x2*>(mid) + base + q * 256);
  }
}

__global__ __launch_bounds__(256) void gather_hi(
    const float* __restrict__ coords,
    const uint2* __restrict__ hi_p,     // [12][512][512] texel = 4 bf16
    const unsigned* __restrict__ mid,
    float* __restrict__ pts) {          // [N*M]x4 {r,g,b,sigma_raw}
  int bid = blockIdx.x;                       // 1536
  int n = (bid & 7) >> 1;
  int blk = ((bid >> 3) << 1) + (bid & 1);
  int base = n * M_PTS + blk * 512 + threadIdx.x;

  float acc[2][4];
#pragma unroll
  for (int q = 0; q < 2; ++q) {
    int idx = base + q * 256;
    u32x2 m = __builtin_nontemporal_load(
        reinterpret_cast<const u32x2*>(mid) + idx);
    float X = __builtin_nontemporal_load(coords + idx * 3 + 0) * 2.f;
    float Y = __builtin_nontemporal_load(coords + idx * 3 + 1) * 2.f;
    float Z = __builtin_nontemporal_load(coords + idx * 3 + 2) * 2.f;
    acc[q][0] = bflo(m.x); acc[q][1] = bfhi(m.x);
    acc[q][2] = bflo(m.y); acc[q][3] = bfhi(m.y);
    const float gxs[3] = {X, X, Y};
    const float gys[3] = {Y, Z, Z};
    const float gzs[3] = {Z, Y, X};
#pragma unroll
    for (int p = 0; p < 3; ++p) {
      float wz = (1.f - 0.5f * fabsf(gzs[p])) * (1.f / 6.f);
      surf_accum(hi_p, (n * 3 + p) << 18, 9, gxs[p], gys[p], wz, acc[q]);
    }
  }
#pragma unroll
  for (int q = 0; q < 2; ++q) {
    f32x4 o;
    o.x = 1.f / (1.f + __expf(-acc[q][1]));
    o.y = 1.f / (1.f + __expf(-acc[q][2]));
    o.z = 1.f / (1.f + __expf(-acc[q][3]));
    o.w = acc[q][0];                          // raw density (pre-softplus)
    __builtin_nontemporal_store(
        o, reinterpret_cast<f32x4*>(pts) + base + q * 256);
  }
}

// ---------------------------------------------------------------------------
// K2: alpha compositing, one thread per ray. 64-thread blocks -> 256 blocks
// so the streaming read spreads across all CUs.
// ---------------------------------------------------------------------------
__global__ __launch_bounds__(64) void ray_march_k(
    const float4* __restrict__ pts, const float* __restrict__ depths,
    float* __restrict__ out) {
  int t = blockIdx.x * 64 + threadIdx.x;     // < N*R
  const float4* p = pts + (size_t)t * S_SAMP;
  const float* d = depths + (size_t)t * S_SAMP;

  float4 prev = p[0];
  float dprev = d[0];
  float T = 1.f, accR = 0.f, accG = 0.f, accB = 0.f;
#pragma unroll 4
  for (int i = 1; i < S_SAMP; ++i) {
    float4 cur = p[i];
    float dcur = d[i];
    float delta = dcur - dprev;
    float cr = 0.5f * (prev.x + cur.x);
    float cg = 0.5f * (prev.y + cur.y);
    float cb = 0.5f * (prev.z + cur.z);
    float dm = 0.5f * (prev.w + cur.w) - 1.f;
    float sp = fmaxf(dm, 0.f) + log1pf(__expf(-fabsf(dm)));  // softplus
    float a = 1.f - __expf(-sp * delta);
    float w = a * T;
    accR += w * cr; accG += w * cg; accB += w * cb;
    T *= (1.f - a + 1e-10f);
    prev = cur; dprev = dcur;
  }
  out[t * 3 + 0] = accR;
  out[t * 3 + 1] = accG;
  out[t * 3 + 2] = accB;
}

// ---------------------------------------------------------------------------
extern "C" void kernel_launch(void* const* d_in, const int* in_sizes, int n_in,
                              void* d_out, int out_size, void* d_ws, size_t ws_size,
                              hipStream_t stream) {
  const float* plane_lo = (const float*)d_in[0];  // [4,3,32,256,256]
  const float* plane_hi = (const float*)d_in[1];  // [4,3,32,512,512]
  const float* coords   = (const float*)d_in[2];  // [4,196608,3]
  const float* depths   = (const float*)d_in[3];  // [4,4096,48,1]
  const float* w_sigma  = (const float*)d_in[4];  // [32,1]
  const float* w_rgb    = (const float*)d_in[5];  // [32,3]

  const size_t LO_TEX = (size_t)12 * 256 * 256;   //   786,432 texels
  const size_t HI_TEX = (size_t)12 * 512 * 512;   // 3,145,728 texels
  char* ws = (char*)d_ws;
  uint2* lo_p = (uint2*)ws;                                     //  6.3 MB
  uint2* hi_p = (uint2*)(ws + LO_TEX * 8);                      // 25.2 MB
  unsigned* mid = (unsigned*)(ws + (LO_TEX + HI_TEX) * 8);      //  6.3 MB
  float* pts = (float*)(ws + (LO_TEX + HI_TEX) * 8
                           + (size_t)TOTAL_PTS * 8);            // 12.6 MB

  project_planes<<<LO_BLOCKS + HI_BLOCKS, 256, 0, stream>>>(
      plane_lo, plane_hi, w_sigma, w_rgb, (uint4*)lo_p, (uint4*)hi_p);

  gather_lo<<<TOTAL_PTS / 512, 256, 0, stream>>>(coords, lo_p, mid);
  gather_hi<<<TOTAL_PTS / 512, 256, 0, stream>>>(coords, hi_p, mid, pts);

  ray_march_k<<<(N_IMG * R_RAYS) / 64, 64, 0, stream>>>(
      (const float4*)pts, depths, (float*)d_out);
}

// Round 10
// 167.280 us; speedup vs baseline: 1.5091x; 1.0326x over previous
//
#include <hip/hip_runtime.h>
#include <hip/hip_bf16.h>
#include <cstdint>

#define N_IMG 4
#define C_CH 32
#define R_RAYS 4096
#define S_SAMP 48
#define M_PTS (R_RAYS * S_SAMP)   // 196608 points per image
#define TOTAL_PTS (N_IMG * M_PTS) // 786432

typedef float f32x4 __attribute__((ext_vector_type(4)));
typedef unsigned int u32x4 __attribute__((ext_vector_type(4)));
typedef unsigned int u32x2 __attribute__((ext_vector_type(2)));

__device__ __forceinline__ unsigned f2bf(float f) {
  __hip_bfloat16 h = __float2bfloat16(f);
  return (unsigned)*reinterpret_cast<unsigned short*>(&h);
}
__device__ __forceinline__ float bflo(unsigned u) { return __uint_as_float(u << 16); }
__device__ __forceinline__ float bfhi(unsigned u) { return __uint_as_float(u & 0xffff0000u); }

// ---------------------------------------------------------------------------
// K0: per-texel head projection, 4 texels/thread, lo+hi in one launch.
// in:  f32 [NP=12, C=32, H, W];  out row-major bf16x4 [NP, H, W] packed texel
// {sig | r<<16, g | b<<16}. Linear heads commute with bilinear sampling and
// plane/level averaging -> gathering the 4 projections is exact up to one
// bf16 rounding. Live-box clip: grid in (-0.9,0.9) -> rows/cols [12,243]
// (W=256) / [25,486] (W=512); +-1 margin kept.
// Input reads are non-temporal (pure streaming, never reused).
// ---------------------------------------------------------------------------
#define LO_BLOCKS 768    // 12*256*256/4/256
#define HI_BLOCKS 3072   // 12*512*512/4/256

__global__ __launch_bounds__(256) void project_planes(
    const float* __restrict__ lo, const float* __restrict__ hi,
    const float* __restrict__ w_sigma, const float* __restrict__ w_rgb,
    uint4* __restrict__ lo_out, uint4* __restrict__ hi_out) {
  __shared__ float sw[4 * C_CH];  // [c*4 + k], k=0 sigma, 1..3 rgb
  int t = threadIdx.x;
  if (t < C_CH) sw[t * 4] = w_sigma[t];
  if (t < 3 * C_CH) sw[(t / 3) * 4 + 1 + (t % 3)] = w_rgb[t];
  __syncthreads();

  int bid = blockIdx.x;
  const float* in;
  uint4* out;
  int logW, g, c0, c1;
  if (bid < LO_BLOCKS) {
    in = lo; out = lo_out; logW = 8; g = bid * 256 + t; c0 = 11; c1 = 244;
  } else {
    in = hi; out = hi_out; logW = 9; g = (bid - LO_BLOCKS) * 256 + t; c0 = 24; c1 = 488;
  }
  int W = 1 << logW;
  int hw = (g * 4) & ((W * W) - 1);
  int np = (g * 4) >> (2 * logW);
  int h = hw >> logW, w = hw & (W - 1);
  if (h < c0 || h > c1 || (w + 3) < c0 || w > c1) return;  // dead margin

  const float* base = in + ((size_t)np << (5 + 2 * logW)) + hw;
  f32x4 as = 0.f, ar = 0.f, ag = 0.f, ab = 0.f;
#pragma unroll
  for (int c = 0; c < C_CH; ++c) {
    f32x4 f = __builtin_nontemporal_load(
        reinterpret_cast<const f32x4*>(base + ((size_t)c << (2 * logW))));
    as += f * sw[c * 4 + 0];
    ar += f * sw[c * 4 + 1];
    ag += f * sw[c * 4 + 2];
    ab += f * sw[c * 4 + 3];
  }
  uint4 o0, o1;
  o0.x = f2bf(as.x) | (f2bf(ar.x) << 16);
  o0.y = f2bf(ag.x) | (f2bf(ab.x) << 16);
  o0.z = f2bf(as.y) | (f2bf(ar.y) << 16);
  o0.w = f2bf(ag.y) | (f2bf(ab.y) << 16);
  o1.x = f2bf(as.z) | (f2bf(ar.z) << 16);
  o1.y = f2bf(ag.z) | (f2bf(ab.z) << 16);
  o1.z = f2bf(as.w) | (f2bf(ar.w) << 16);
  o1.w = f2bf(ag.w) | (f2bf(ab.w) << 16);
  out[g * 2 + 0] = o0;
  out[g * 2 + 1] = o1;
}

// ---------------------------------------------------------------------------
// K1: single gather pass over all 6 surfaces (3 lo + 3 hi), 2 pts/thread.
// XCD-image affinity: bid&7 -> XCD (round-robin dispatch), (bid&7)>>1 pins
// each XCD to one image -> texel working set/XCD = 1.5MB(lo)+2MB(hi) < 4MB L2.
// coords/pts use non-temporal hints so streams don't evict texels.
// ---------------------------------------------------------------------------
__device__ __forceinline__ void surf_accum(
    const uint2* __restrict__ tex, int pb, int logW,
    float gx, float gy, float wz, float* acc) {
  const int W = 1 << logW;
  float xf = ((gx + 1.f) * (float)W - 1.f) * 0.5f;
  float yf = ((gy + 1.f) * (float)W - 1.f) * 0.5f;
  float x0f = floorf(xf), y0f = floorf(yf);
  float fx = xf - x0f, fy = yf - y0f;
  int x0 = (int)x0f, y0 = (int)y0f;
  x0 = min(max(x0, 0), W - 2);               // inputs interior; OOB safety
  y0 = min(max(y0, 0), W - 2);
  int base = pb + (y0 << logW) + x0;
  u32x4 r0, r1;
  __builtin_memcpy(&r0, tex + base, 16);     // texels (y0,   x0..x0+1)
  __builtin_memcpy(&r1, tex + base + W, 16); // texels (y0+1, x0..x0+1)
  float w00 = wz * (1.f - fy) * (1.f - fx);
  float w01 = wz * (1.f - fy) * fx;
  float w10 = wz * fy * (1.f - fx);
  float w11 = wz * fy * fx;
  acc[0] += w00 * bflo(r0.x) + w01 * bflo(r0.z) + w10 * bflo(r1.x) + w11 * bflo(r1.z);
  acc[1] += w00 * bfhi(r0.x) + w01 * bfhi(r0.z) + w10 * bfhi(r1.x) + w11 * bfhi(r1.z);
  acc[2] += w00 * bflo(r0.y) + w01 * bflo(r0.w) + w10 * bflo(r1.y) + w11 * bflo(r1.w);
  acc[3] += w00 * bfhi(r0.y) + w01 * bfhi(r0.w) + w10 * bfhi(r1.y) + w11 * bfhi(r1.w);
}

__global__ __launch_bounds__(256) void gather_all(
    const float* __restrict__ coords,
    const uint2* __restrict__ lo_p,     // [12][256][256] texel = 4 bf16
    const uint2* __restrict__ hi_p,     // [12][512][512]
    float* __restrict__ pts) {          // [N*M]x4 {r,g,b,sigma_raw}
  int bid = blockIdx.x;                       // 1536
  int n = (bid & 7) >> 1;                     // image per XCD pair
  int blk = ((bid >> 3) << 1) + (bid & 1);    // 0..383 within image
  int base = n * M_PTS + blk * 512 + threadIdx.x;

  float acc[2][4];
#pragma unroll
  for (int q = 0; q < 2; ++q) {
    int idx = base + q * 256;
    float X = __builtin_nontemporal_load(coords + idx * 3 + 0) * 2.f;
    float Y = __builtin_nontemporal_load(coords + idx * 3 + 1) * 2.f;
    float Z = __builtin_nontemporal_load(coords + idx * 3 + 2) * 2.f;
    acc[q][0] = 0.f; acc[q][1] = 0.f; acc[q][2] = 0.f; acc[q][3] = 0.f;
    const float gxs[3] = {X, X, Y};
    const float gys[3] = {Y, Z, Z};
    const float gzs[3] = {Z, Y, X};
#pragma unroll
    for (int p = 0; p < 3; ++p) {
      float wz = (1.f - 0.5f * fabsf(gzs[p])) * (1.f / 6.f);
      surf_accum(lo_p, (n * 3 + p) << 16, 8, gxs[p], gys[p], wz, acc[q]);
    }
#pragma unroll
    for (int p = 0; p < 3; ++p) {
      float wz = (1.f - 0.5f * fabsf(gzs[p])) * (1.f / 6.f);
      surf_accum(hi_p, (n * 3 + p) << 18, 9, gxs[p], gys[p], wz, acc[q]);
    }
  }
#pragma unroll
  for (int q = 0; q < 2; ++q) {
    f32x4 o;
    o.x = 1.f / (1.f + __expf(-acc[q][1]));
    o.y = 1.f / (1.f + __expf(-acc[q][2]));
    o.z = 1.f / (1.f + __expf(-acc[q][3]));
    o.w = acc[q][0];                          // raw density (pre-softplus)
    __builtin_nontemporal_store(
        o, reinterpret_cast<f32x4*>(pts) + base + q * 256);
  }
}

// ---------------------------------------------------------------------------
// K2: alpha compositing, one thread per ray. 64-thread blocks -> 256 blocks
// so the streaming read spreads across all CUs.
// ---------------------------------------------------------------------------
__global__ __launch_bounds__(64) void ray_march_k(
    const float4* __restrict__ pts, const float* __restrict__ depths,
    float* __restrict__ out) {
  int t = blockIdx.x * 64 + threadIdx.x;     // < N*R
  const float4* p = pts + (size_t)t * S_SAMP;
  const float* d = depths + (size_t)t * S_SAMP;

  float4 prev = p[0];
  float dprev = d[0];
  float T = 1.f, accR = 0.f, accG = 0.f, accB = 0.f;
#pragma unroll 4
  for (int i = 1; i < S_SAMP; ++i) {
    float4 cur = p[i];
    float dcur = d[i];
    float delta = dcur - dprev;
    float cr = 0.5f * (prev.x + cur.x);
    float cg = 0.5f * (prev.y + cur.y);
    float cb = 0.5f * (prev.z + cur.z);
    float dm = 0.5f * (prev.w + cur.w) - 1.f;
    float sp = fmaxf(dm, 0.f) + log1pf(__expf(-fabsf(dm)));  // softplus
    float a = 1.f - __expf(-sp * delta);
    float w = a * T;
    accR += w * cr; accG += w * cg; accB += w * cb;
    T *= (1.f - a + 1e-10f);
    prev = cur; dprev = dcur;
  }
  out[t * 3 + 0] = accR;
  out[t * 3 + 1] = accG;
  out[t * 3 + 2] = accB;
}

// ---------------------------------------------------------------------------
extern "C" void kernel_launch(void* const* d_in, const int* in_sizes, int n_in,
                              void* d_out, int out_size, void* d_ws, size_t ws_size,
                              hipStream_t stream) {
  const float* plane_lo = (const float*)d_in[0];  // [4,3,32,256,256]
  const float* plane_hi = (const float*)d_in[1];  // [4,3,32,512,512]
  const float* coords   = (const float*)d_in[2];  // [4,196608,3]
  const float* depths   = (const float*)d_in[3];  // [4,4096,48,1]
  const float* w_sigma  = (const float*)d_in[4];  // [32,1]
  const float* w_rgb    = (const float*)d_in[5];  // [32,3]

  const size_t LO_TEX = (size_t)12 * 256 * 256;   //   786,432 texels
  const size_t HI_TEX = (size_t)12 * 512 * 512;   // 3,145,728 texels
  char* ws = (char*)d_ws;
  uint2* lo_p = (uint2*)ws;                                     //  6.3 MB
  uint2* hi_p = (uint2*)(ws + LO_TEX * 8);                      // 25.2 MB
  float* pts = (float*)(ws + (LO_TEX + HI_TEX) * 8);            // 12.6 MB

  project_planes<<<LO_BLOCKS + HI_BLOCKS, 256, 0, stream>>>(
      plane_lo, plane_hi, w_sigma, w_rgb, (uint4*)lo_p, (uint4*)hi_p);

  gather_all<<<TOTAL_PTS / 512, 256, 0, stream>>>(coords, lo_p, hi_p, pts);

  ray_march_k<<<(N_IMG * R_RAYS) / 64, 64, 0, stream>>>(
      (const float4*)pts, depths, (float*)d_out);
}